// Round 2
// baseline (91.132 us; speedup 1.0000x reference)
//
#include <hip/hip_runtime.h>
#include <hip/hip_bf16.h>

// Problem constants: B=16, TV=128, TH=64, F=512, H=512, D=256
#define BB 16
#define TV 128
#define TH 64
#define FF 512
#define HH 512
#define DD 256

#define LOG2E2 2.8853900817779268f   // 2*log2(e): exp2(LOG2E2*x) = e^{2x}

typedef __attribute__((ext_vector_type(8))) short bf16x8;   // 8 bf16 = 4 VGPRs
typedef __attribute__((ext_vector_type(4))) float f32x4;

__device__ __forceinline__ float fast_exp2(float x) {
#if __has_builtin(__builtin_amdgcn_exp2f)
  return __builtin_amdgcn_exp2f(x);
#else
  return __expf(x * 0.6931471805599453f);
#endif
}
__device__ __forceinline__ float fast_rcp(float x) {
#if __has_builtin(__builtin_amdgcn_rcpf)
  return __builtin_amdgcn_rcpf(x);
#else
  return 1.0f / x;
#endif
}
__device__ __forceinline__ unsigned short f2bf(float x) {  // RNE fp32->bf16
  union { float f; unsigned u; } a; a.f = x;
  unsigned r = a.u + 0x7fffu + ((a.u >> 16) & 1u);
  return (unsigned short)(r >> 16);
}

// pack 8 f32 -> bf16x8 (RNE; compiler emits packed cvt — m240: scalar casts
// beat hand-written inline-asm cvt_pk)
__device__ __forceinline__ bf16x8 cvt8(const float4 x, const float4 y) {
  union { bf16x8 v; unsigned short e[8]; } r;
  r.e[0] = f2bf(x.x); r.e[1] = f2bf(x.y); r.e[2] = f2bf(x.z); r.e[3] = f2bf(x.w);
  r.e[4] = f2bf(y.x); r.e[5] = f2bf(y.y); r.e[6] = f2bf(y.z); r.e[7] = f2bf(y.w);
  return r.v;
}

// ---------------------------------------------------------------------------
// Mini convert: W,U -> bf16 TRANSPOSED ([n][k]) only. v/h conversion is now
// folded into the GEMM (in-register cvt), removing 9 MB of staging traffic.
// 65536 tasks, 256 blocks x 256 thr.
// ---------------------------------------------------------------------------
__global__ __launch_bounds__(256) void convert_wu_kernel(
    const float* __restrict__ W, const float* __restrict__ U,
    unsigned short* __restrict__ WT, unsigned short* __restrict__ UT) {
  int t2 = blockIdx.x * 256 + threadIdx.x;
  const float* S;
  unsigned short* Dt;
  if (t2 < 32768) { S = W; Dt = WT; } else { S = U; Dt = UT; t2 -= 32768; }
  int n = t2 & 255, k4 = t2 >> 8;           // k4 in [0,128)
  float a0 = S[(k4 * 4 + 0) * 256 + n];     // coalesced over n
  float a1 = S[(k4 * 4 + 1) * 256 + n];
  float a2 = S[(k4 * 4 + 2) * 256 + n];
  float a3 = S[(k4 * 4 + 3) * 256 + n];
  ushort4 o = make_ushort4(f2bf(a0), f2bf(a1), f2bf(a2), f2bf(a3));
  *(ushort4*)&Dt[(size_t)n * 512 + k4 * 4] = o;
}

// ---------------------------------------------------------------------------
// MFMA GEMM, no LDS, no barriers. 384 blocks * 64 thr (1 wave).
//   blocks [0,256):   EaT[b][d][t]  = exp2(LOG2E2 * (v @ W))   (TRANSPOSED)
//   blocks [256,384): EuhT[m][d]    = exp2(LOG2E2 * (h @ U + b))
// A loaded as f32 DIRECTLY (no staging kernel) + in-register bf16 cvt.
// Wave tile: 32m x 64n x 512k via 2x4 of mfma_f32_16x16x32_bf16 — the 64-wide
// n halves A re-reads (x4 instead of x8), paying for the f32 A width.
// C/D: col = l&15, row = (l>>4)*4 + reg   (m89-verified)
// ---------------------------------------------------------------------------
__global__ __launch_bounds__(64) void mfma_gemm_kernel(
    const float* __restrict__ Av, const float* __restrict__ Ah,
    const unsigned short* __restrict__ WT, const unsigned short* __restrict__ UT,
    const float* __restrict__ bias, float* __restrict__ EaT,
    float* __restrict__ EuhT) {
  const int bid = blockIdx.x;
  const float* A;
  const unsigned short* BT;
  int mt, nt;
  bool is_wv;
  if (bid < 256) {
    A = Av; BT = WT; is_wv = true;
    mt = bid >> 2; nt = bid & 3;            // mt 0..63, nt 0..3
  } else {
    const int b2 = bid - 256;
    A = Ah; BT = UT; is_wv = false;
    mt = b2 >> 2; nt = b2 & 3;              // mt 0..31
  }
  const int lane = threadIdx.x & 63;
  const int m0   = mt * 32;
  const int n0   = nt * 64;
  const int r16  = lane & 15;
  const int quad = lane >> 4;

  const float* a0p = A + (size_t)(m0 + r16) * 512 + quad * 8;
  const float* a1p = a0p + 16 * 512;
  const unsigned short* bp0 = BT + (size_t)(n0 + r16) * 512 + quad * 8;
  const unsigned short* bp1 = bp0 + 16 * 512;
  const unsigned short* bp2 = bp0 + 32 * 512;
  const unsigned short* bp3 = bp0 + 48 * 512;

  f32x4 acc[2][4];
#pragma unroll
  for (int i = 0; i < 2; i++)
#pragma unroll
    for (int j = 0; j < 4; j++) acc[i][j] = (f32x4){0.f, 0.f, 0.f, 0.f};

#pragma unroll
  for (int kc = 0; kc < 16; kc++) {
    float4 a0lo = *(const float4*)(a0p + kc * 32);
    float4 a0hi = *(const float4*)(a0p + kc * 32 + 4);
    float4 a1lo = *(const float4*)(a1p + kc * 32);
    float4 a1hi = *(const float4*)(a1p + kc * 32 + 4);
    bf16x8 fa0 = cvt8(a0lo, a0hi);
    bf16x8 fa1 = cvt8(a1lo, a1hi);
    bf16x8 fb0 = *(const bf16x8*)(bp0 + kc * 32);
    bf16x8 fb1 = *(const bf16x8*)(bp1 + kc * 32);
    bf16x8 fb2 = *(const bf16x8*)(bp2 + kc * 32);
    bf16x8 fb3 = *(const bf16x8*)(bp3 + kc * 32);
    acc[0][0] = __builtin_amdgcn_mfma_f32_16x16x32_bf16(fa0, fb0, acc[0][0], 0, 0, 0);
    acc[0][1] = __builtin_amdgcn_mfma_f32_16x16x32_bf16(fa0, fb1, acc[0][1], 0, 0, 0);
    acc[0][2] = __builtin_amdgcn_mfma_f32_16x16x32_bf16(fa0, fb2, acc[0][2], 0, 0, 0);
    acc[0][3] = __builtin_amdgcn_mfma_f32_16x16x32_bf16(fa0, fb3, acc[0][3], 0, 0, 0);
    acc[1][0] = __builtin_amdgcn_mfma_f32_16x16x32_bf16(fa1, fb0, acc[1][0], 0, 0, 0);
    acc[1][1] = __builtin_amdgcn_mfma_f32_16x16x32_bf16(fa1, fb1, acc[1][1], 0, 0, 0);
    acc[1][2] = __builtin_amdgcn_mfma_f32_16x16x32_bf16(fa1, fb2, acc[1][2], 0, 0, 0);
    acc[1][3] = __builtin_amdgcn_mfma_f32_16x16x32_bf16(fa1, fb3, acc[1][3], 0, 0, 0);
  }

  if (is_wv) {
    // transposed store: EaT[b*32768 + d*128 + t], d = n-col, t = m&127
    const int bb = m0 >> 7;
    const int tb = (m0 & 127) + quad * 4;       // + 16*i + r below
    float* Wb = EaT + (size_t)bb * 32768;
#pragma unroll
    for (int i = 0; i < 2; i++) {
#pragma unroll
      for (int j = 0; j < 4; j++) {
#pragma unroll
        for (int r = 0; r < 4; r++) {
          Wb[(size_t)(n0 + 16 * j + r16) * 128 + tb + 16 * i + r] =
              fast_exp2(acc[i][j][r] * LOG2E2);
        }
      }
    }
  } else {
    float bj[4];
#pragma unroll
    for (int j = 0; j < 4; j++) bj[j] = bias[n0 + 16 * j + r16];
#pragma unroll
    for (int i = 0; i < 2; i++) {
#pragma unroll
      for (int j = 0; j < 4; j++) {
#pragma unroll
        for (int r = 0; r < 4; r++) {
          const int row = m0 + 16 * i + quad * 4 + r;
          EuhT[(size_t)row * 256 + n0 + 16 * j + r16] =
              fast_exp2((acc[i][j][r] + bj[j]) * LOG2E2);
        }
      }
    }
  }
}

// ---------------------------------------------------------------------------
// Fused attention. 256 blocks, 1024 thr. XCD-swizzled so all 16 sg-blocks of
// a batch b land on one XCD (v[b]+EaT[b] become XCD-L2-resident).
// Score: thread = (dgf:32, t4:32). Each thread owns 8 d's, 4 t's, ALL 4 s's:
//   Ea float4 loaded ONCE and reused for 4 s.
//   sigmoid denominators D = 1 + Ea*Euh (exp2 pre-hoisted into GEMM).
//   Pairwise rcp merge: w0/D0 + w1/D1 = (w0*D1+w1*D0)/(D0*D1) -> rcps halved.
//   Cross-dgf: shfl_xor(32) pairs dgf 2w/2w+1, then pS[4][16][128] in LDS.
// Softmax over t: threads<512, wave shuffle + 2-wave LDS combine.
// Context: thread = (f:512, th:2); th = t-half, ALL 4 s-rows per thread —
//   v loads per thread halve vs (f,sh) layout (no duplicate v reads);
//   partial u combined via LDS (reusing pS) + one barrier.
// ---------------------------------------------------------------------------
__global__ __launch_bounds__(1024) void attn_fused_kernel(
    const float* __restrict__ EaT, const float* __restrict__ EuhT,
    const float* __restrict__ wg, const float* __restrict__ v,
    float* __restrict__ u) {
  __shared__ float EuhS[4 * 256];
  __shared__ float wS[256];
  __shared__ float pS[4 * 16 * 128];   // [s][wavepair][t]; reused as uP[2][4][512]
  __shared__ float bS[4 * 128];
  __shared__ float mW[8];
  __shared__ float sW[8];

  const int tid = threadIdx.x;
  // bijective XCD swizzle: round-robin dispatch puts bid&7 on XCD (bid&7);
  // give each XCD 2 full b's (16 sg-blocks each).
  const int bid  = blockIdx.x;
  const int slot = bid >> 3;
  const int b    = (bid & 7) * 2 + (slot >> 4);
  const int sg   = slot & 15;
  const int s0   = sg * 4;

  // ---- stage Euh (4x256, already exp2'd) and w (256) ----
  if (tid < 256) {
    const int row = tid >> 6, q4 = (tid & 63) << 2;
    *(float4*)&EuhS[row * 256 + q4] =
        *(const float4*)&EuhT[(size_t)(b * 64 + s0 + row) * 256 + q4];
  } else if (tid < 320) {
    const int q4 = (tid - 256) << 2;
    *(float4*)&wS[q4] = *(const float4*)&wg[q4];
  }
  __syncthreads();

  // ---- scores: thread = (dgf, t4); 8 d x 4 t x 4 s each ----
  {
    const int t4  = tid & 31;
    const int dgf = tid >> 5;                     // 0..31
    const float* eab = EaT + (size_t)b * 32768 + (size_t)dgf * 8 * 128 + t4 * 4;

    // preload Euh (4s x 8d) and w (8d) into registers (static-indexed)
    float eu[4][8];
    float wr[8];
#pragma unroll
    for (int s = 0; s < 4; s++) {
      *(float4*)&eu[s][0] = *(const float4*)&EuhS[s * 256 + dgf * 8];
      *(float4*)&eu[s][4] = *(const float4*)&EuhS[s * 256 + dgf * 8 + 4];
    }
    *(float4*)&wr[0] = *(const float4*)&wS[dgf * 8];
    *(float4*)&wr[4] = *(const float4*)&wS[dgf * 8 + 4];

    f32x4 acc[4];
#pragma unroll
    for (int s = 0; s < 4; s++) acc[s] = (f32x4){0.f, 0.f, 0.f, 0.f};

#pragma unroll
    for (int jp = 0; jp < 4; jp++) {            // 4 d-pairs
      float4 e0 = *(const float4*)(eab + (2 * jp + 0) * 128);
      float4 e1 = *(const float4*)(eab + (2 * jp + 1) * 128);
      const float w0 = wr[2 * jp], w1 = wr[2 * jp + 1];
#pragma unroll
      for (int s = 0; s < 4; s++) {
        const float u0 = eu[s][2 * jp], u1 = eu[s][2 * jp + 1];
        float D0, D1, num;
        D0 = fmaf(e0.x, u0, 1.0f); D1 = fmaf(e1.x, u1, 1.0f);
        num = fmaf(w1, D0, w0 * D1);
        acc[s][0] = fmaf(num, fast_rcp(D0 * D1), acc[s][0]);
        D0 = fmaf(e0.y, u0, 1.0f); D1 = fmaf(e1.y, u1, 1.0f);
        num = fmaf(w1, D0, w0 * D1);
        acc[s][1] = fmaf(num, fast_rcp(D0 * D1), acc[s][1]);
        D0 = fmaf(e0.z, u0, 1.0f); D1 = fmaf(e1.z, u1, 1.0f);
        num = fmaf(w1, D0, w0 * D1);
        acc[s][2] = fmaf(num, fast_rcp(D0 * D1), acc[s][2]);
        D0 = fmaf(e0.w, u0, 1.0f); D1 = fmaf(e1.w, u1, 1.0f);
        num = fmaf(w1, D0, w0 * D1);
        acc[s][3] = fmaf(num, fast_rcp(D0 * D1), acc[s][3]);
      }
    }

    // combine dgf pair (2w, 2w+1): lane l += lane l^32
#pragma unroll
    for (int s = 0; s < 4; s++) {
#pragma unroll
      for (int c = 0; c < 4; c++) acc[s][c] += __shfl_xor(acc[s][c], 32, 64);
    }
    const int wv_ = tid >> 6;                   // 0..15
    if ((tid & 63) < 32) {
#pragma unroll
      for (int s = 0; s < 4; s++) {
        float4 o = make_float4(acc[s][0], acc[s][1], acc[s][2], acc[s][3]);
        *(float4*)&pS[(s * 16 + wv_) * 128 + t4 * 4] = o;
      }
    }
  }
  __syncthreads();

  // ---- reduce over 16 wavepairs + softmax over t (threads < 512) ----
  float qv = 0.0f, ev = 0.0f;
  const int wvid = tid >> 6, lane = tid & 63;
  if (tid < 512) {
    const int s_l = tid >> 7, t = tid & 127;
    float ssum = 0.0f;
#pragma unroll
    for (int k = 0; k < 16; k++) ssum += pS[(s_l * 16 + k) * 128 + t];
    qv = ssum * (-LOG2E2);   // log2-domain score
    float m = qv;
#pragma unroll
    for (int off = 32; off > 0; off >>= 1) m = fmaxf(m, __shfl_xor(m, off, 64));
    if (lane == 0) mW[wvid] = m;
  }
  __syncthreads();
  if (tid < 512) {
    float m = fmaxf(mW[wvid], mW[wvid ^ 1]);
    ev = fast_exp2(qv - m);
    float ssum = ev;
#pragma unroll
    for (int off = 32; off > 0; off >>= 1) ssum += __shfl_xor(ssum, off, 64);
    if (lane == 0) sW[wvid] = ssum;
  }
  __syncthreads();
  if (tid < 512) {
    const int s_l = tid >> 7, t = tid & 127;
    bS[s_l * 128 + t] = ev * fast_rcp(sW[wvid] + sW[wvid ^ 1]);
  }
  __syncthreads();

  // ---- context: thread = (f:512, th:2); th = t-half, all 4 s-rows ----
  const int f  = tid & 511;
  const int th = tid >> 9;
  const float* vb2 = v + (size_t)b * TV * FF + (size_t)th * 64 * FF;
  const float* bsp = &bS[th * 64];
  float a0 = 0.f, a1 = 0.f, a2 = 0.f, a3 = 0.f;
#pragma unroll 4
  for (int tg = 0; tg < 64; tg += 4) {
    float4 b0 = *(const float4*)&bsp[0 * 128 + tg];
    float4 b1 = *(const float4*)&bsp[1 * 128 + tg];
    float4 b2 = *(const float4*)&bsp[2 * 128 + tg];
    float4 b3 = *(const float4*)&bsp[3 * 128 + tg];
    float v0 = vb2[(tg + 0) * 512 + f];
    float v1 = vb2[(tg + 1) * 512 + f];
    float v2 = vb2[(tg + 2) * 512 + f];
    float v3 = vb2[(tg + 3) * 512 + f];
    a0 = fmaf(b0.x, v0, a0); a0 = fmaf(b0.y, v1, a0);
    a0 = fmaf(b0.z, v2, a0); a0 = fmaf(b0.w, v3, a0);
    a1 = fmaf(b1.x, v0, a1); a1 = fmaf(b1.y, v1, a1);
    a1 = fmaf(b1.z, v2, a1); a1 = fmaf(b1.w, v3, a1);
    a2 = fmaf(b2.x, v0, a2); a2 = fmaf(b2.y, v1, a2);
    a2 = fmaf(b2.z, v2, a2); a2 = fmaf(b2.w, v3, a2);
    a3 = fmaf(b3.x, v0, a3); a3 = fmaf(b3.y, v1, a3);
    a3 = fmaf(b3.z, v2, a3); a3 = fmaf(b3.w, v3, a3);
  }
  // partials -> LDS (reuse pS as uP[th][s][f]); conflict-free (consecutive f)
  float* uP = pS;
  uP[(th * 4 + 0) * 512 + f] = a0;
  uP[(th * 4 + 1) * 512 + f] = a1;
  uP[(th * 4 + 2) * 512 + f] = a2;
  uP[(th * 4 + 3) * 512 + f] = a3;
  __syncthreads();
  // combine halves + store: 2048 outputs, 2 per thread, coalesced over f
  {
    int oi = tid;
#pragma unroll
    for (int rep = 0; rep < 2; rep++, oi += 1024) {
      const int s = oi >> 9, ff = oi & 511;
      const float val = uP[s * 512 + ff] + uP[(s + 4) * 512 + ff];
      u[(size_t)(b * 64 + s0 + s) * 512 + ff] = val;
    }
  }
}

extern "C" void kernel_launch(void* const* d_in, const int* in_sizes, int n_in,
                              void* d_out, int out_size, void* d_ws, size_t ws_size,
                              hipStream_t stream) {
  const float* v  = (const float*)d_in[0];  // [16,128,512]
  const float* h  = (const float*)d_in[1];  // [16,64,512]
  const float* W  = (const float*)d_in[2];  // [512,256]
  const float* U  = (const float*)d_in[3];  // [512,256]
  const float* bb = (const float*)d_in[4];  // [256]
  const float* w  = (const float*)d_in[5];  // [256,1]
  float* u = (float*)d_out;                 // [16,64,512]

  float* EaT  = (float*)d_ws;                      // [16][256][128] f32 = exp2(2Wv*log2e)
  float* EuhT = EaT + (size_t)2048 * 256;          // [1024,256] f32 = exp2(2(Uh+b)*log2e)
  unsigned short* WT = (unsigned short*)(EuhT + (size_t)1024 * 256);  // [256][512] bf16 (W^T)
  unsigned short* UT = WT + (size_t)256 * 512;                        // [256][512] bf16 (U^T)

  convert_wu_kernel<<<256, 256, 0, stream>>>(W, U, WT, UT);
  mfma_gemm_kernel<<<384, 64, 0, stream>>>(v, h, WT, UT, bb, EaT, EuhT);
  attn_fused_kernel<<<256, 1024, 0, stream>>>(EaT, EuhT, w, v, u);
}

// Round 3
// 88.365 us; speedup vs baseline: 1.0313x; 1.0313x over previous
//
#include <hip/hip_runtime.h>
#include <hip/hip_bf16.h>

// Problem constants: B=16, TV=128, TH=64, F=512, H=512, D=256
#define BB 16
#define TV 128
#define TH 64
#define FF 512
#define HH 512
#define DD 256

#define LOG2E2 2.8853900817779268f   // 2*log2(e): exp2(LOG2E2*x) = e^{2x}

typedef __attribute__((ext_vector_type(8))) short bf16x8;   // 8 bf16 = 4 VGPRs
typedef __attribute__((ext_vector_type(4))) float f32x4;

__device__ __forceinline__ float fast_exp2(float x) {
#if __has_builtin(__builtin_amdgcn_exp2f)
  return __builtin_amdgcn_exp2f(x);
#else
  return __expf(x * 0.6931471805599453f);
#endif
}
__device__ __forceinline__ float fast_rcp(float x) {
#if __has_builtin(__builtin_amdgcn_rcpf)
  return __builtin_amdgcn_rcpf(x);
#else
  return 1.0f / x;
#endif
}
__device__ __forceinline__ unsigned short f2bf(float x) {  // RNE fp32->bf16
  union { float f; unsigned u; } a; a.f = x;
  unsigned r = a.u + 0x7fffu + ((a.u >> 16) & 1u);
  return (unsigned short)(r >> 16);
}

// pack 8 f32 -> bf16x8 (RNE; compiler emits packed cvt — m240: scalar casts
// beat hand-written inline-asm cvt_pk)
__device__ __forceinline__ bf16x8 cvt8(const float4 x, const float4 y) {
  union { bf16x8 v; unsigned short e[8]; } r;
  r.e[0] = f2bf(x.x); r.e[1] = f2bf(x.y); r.e[2] = f2bf(x.z); r.e[3] = f2bf(x.w);
  r.e[4] = f2bf(y.x); r.e[5] = f2bf(y.y); r.e[6] = f2bf(y.z); r.e[7] = f2bf(y.w);
  return r.v;
}

// ---------------------------------------------------------------------------
// Mini convert: W,U -> bf16 TRANSPOSED ([n][k]) only. v/h are consumed as f32
// directly by the GEMM (in-register cvt). 65536 tasks, 256 blocks x 256 thr.
// ---------------------------------------------------------------------------
__global__ __launch_bounds__(256) void convert_wu_kernel(
    const float* __restrict__ W, const float* __restrict__ U,
    unsigned short* __restrict__ WT, unsigned short* __restrict__ UT) {
  int t2 = blockIdx.x * 256 + threadIdx.x;
  const float* S;
  unsigned short* Dt;
  if (t2 < 32768) { S = W; Dt = WT; } else { S = U; Dt = UT; t2 -= 32768; }
  int n = t2 & 255, k4 = t2 >> 8;           // k4 in [0,128)
  float a0 = S[(k4 * 4 + 0) * 256 + n];     // coalesced over n
  float a1 = S[(k4 * 4 + 1) * 256 + n];
  float a2 = S[(k4 * 4 + 2) * 256 + n];
  float a3 = S[(k4 * 4 + 3) * 256 + n];
  ushort4 o = make_ushort4(f2bf(a0), f2bf(a1), f2bf(a2), f2bf(a3));
  *(ushort4*)&Dt[(size_t)n * 512 + k4 * 4] = o;
}

// ---------------------------------------------------------------------------
// MFMA GEMM with 4-way K-split. 384 blocks * 256 thr (4 waves).
//   blocks [0,256):   EaT[b][d][t]  = exp2(LOG2E2 * (v @ W))   (TRANSPOSED)
//   blocks [256,384): EuhT[m][d]    = exp2(LOG2E2 * (h @ U + b))
// Block tile 32m x 64n x 512k; wave wv owns k in [wv*128, wv*128+128).
// K-split rationale (R2 post-mortem): 1.5 waves/CU was latency-bound on
// HBM-cold A reads. K-split gives 1536 waves (6/CU) with per-wave chain of
// only 4 kc rounds (all ~32 loads hoistable in one vmcnt window), and LESS
// total traffic (48 MB vs 72 MB) than shrinking tiles.
// Partials combined via 32 KB LDS; epilogue split across the 4 waves.
// C/D: col = l&15, row = (l>>4)*4 + reg   (m89-verified)
// ---------------------------------------------------------------------------
__global__ __launch_bounds__(256) void mfma_gemm_kernel(
    const float* __restrict__ Av, const float* __restrict__ Ah,
    const unsigned short* __restrict__ WT, const unsigned short* __restrict__ UT,
    const float* __restrict__ bias, float* __restrict__ EaT,
    float* __restrict__ EuhT) {
  __shared__ f32x4 cS[8][4][64];   // [slot=(i*4+j)][wv][lane]
  const int bid = blockIdx.x;
  const float* A;
  const unsigned short* BT;
  int mt, nt;
  bool is_wv;
  if (bid < 256) {
    A = Av; BT = WT; is_wv = true;
    mt = bid >> 2; nt = bid & 3;            // mt 0..63, nt 0..3
  } else {
    const int b2 = bid - 256;
    A = Ah; BT = UT; is_wv = false;
    mt = b2 >> 2; nt = b2 & 3;              // mt 0..31
  }
  const int tid  = threadIdx.x;
  const int wv   = tid >> 6;               // k-split index 0..3
  const int lane = tid & 63;
  const int m0   = mt * 32;
  const int n0   = nt * 64;
  const int r16  = lane & 15;
  const int quad = lane >> 4;

  const float* ap0 = A + (size_t)(m0 + r16) * 512 + wv * 128 + quad * 8;
  const float* ap1 = ap0 + 16 * 512;
  const unsigned short* bp0 = BT + (size_t)(n0 + r16) * 512 + wv * 128 + quad * 8;
  const unsigned short* bp1 = bp0 + 16 * 512;
  const unsigned short* bp2 = bp0 + 32 * 512;
  const unsigned short* bp3 = bp0 + 48 * 512;

  f32x4 acc[2][4];
#pragma unroll
  for (int i = 0; i < 2; i++)
#pragma unroll
    for (int j = 0; j < 4; j++) acc[i][j] = (f32x4){0.f, 0.f, 0.f, 0.f};

#pragma unroll
  for (int kc = 0; kc < 4; kc++) {          // 4 x 32k = this wave's 128k slice
    float4 a0lo = *(const float4*)(ap0 + kc * 32);
    float4 a0hi = *(const float4*)(ap0 + kc * 32 + 4);
    float4 a1lo = *(const float4*)(ap1 + kc * 32);
    float4 a1hi = *(const float4*)(ap1 + kc * 32 + 4);
    bf16x8 fa0 = cvt8(a0lo, a0hi);
    bf16x8 fa1 = cvt8(a1lo, a1hi);
    bf16x8 fb0 = *(const bf16x8*)(bp0 + kc * 32);
    bf16x8 fb1 = *(const bf16x8*)(bp1 + kc * 32);
    bf16x8 fb2 = *(const bf16x8*)(bp2 + kc * 32);
    bf16x8 fb3 = *(const bf16x8*)(bp3 + kc * 32);
    acc[0][0] = __builtin_amdgcn_mfma_f32_16x16x32_bf16(fa0, fb0, acc[0][0], 0, 0, 0);
    acc[0][1] = __builtin_amdgcn_mfma_f32_16x16x32_bf16(fa0, fb1, acc[0][1], 0, 0, 0);
    acc[0][2] = __builtin_amdgcn_mfma_f32_16x16x32_bf16(fa0, fb2, acc[0][2], 0, 0, 0);
    acc[0][3] = __builtin_amdgcn_mfma_f32_16x16x32_bf16(fa0, fb3, acc[0][3], 0, 0, 0);
    acc[1][0] = __builtin_amdgcn_mfma_f32_16x16x32_bf16(fa1, fb0, acc[1][0], 0, 0, 0);
    acc[1][1] = __builtin_amdgcn_mfma_f32_16x16x32_bf16(fa1, fb1, acc[1][1], 0, 0, 0);
    acc[1][2] = __builtin_amdgcn_mfma_f32_16x16x32_bf16(fa1, fb2, acc[1][2], 0, 0, 0);
    acc[1][3] = __builtin_amdgcn_mfma_f32_16x16x32_bf16(fa1, fb3, acc[1][3], 0, 0, 0);
  }

  // ---- K-partial exchange: all 4 waves write, epilogue split by slot ----
#pragma unroll
  for (int i = 0; i < 2; i++)
#pragma unroll
    for (int j = 0; j < 4; j++) cS[i * 4 + j][wv][lane] = acc[i][j];
  __syncthreads();

#pragma unroll
  for (int rep = 0; rep < 2; rep++) {
    const int slot = wv + rep * 4;          // wave wv handles slots wv, wv+4
    const int i = slot >> 2, j = slot & 3;
    f32x4 s0 = cS[slot][0][lane];
    f32x4 s1 = cS[slot][1][lane];
    f32x4 s2 = cS[slot][2][lane];
    f32x4 s3 = cS[slot][3][lane];
    f32x4 sum = (s0 + s1) + (s2 + s3);
    if (is_wv) {
      // transposed store: EaT[b*32768 + d*128 + t], d = n-col, t = m&127
      const int bb = m0 >> 7;
      const int tb = (m0 & 127) + 16 * i + quad * 4;
      float* Wb = EaT + (size_t)bb * 32768;
#pragma unroll
      for (int r = 0; r < 4; r++) {
        Wb[(size_t)(n0 + 16 * j + r16) * 128 + tb + r] =
            fast_exp2(sum[r] * LOG2E2);
      }
    } else {
      const float bj = bias[n0 + 16 * j + r16];
#pragma unroll
      for (int r = 0; r < 4; r++) {
        const int row = m0 + 16 * i + quad * 4 + r;
        EuhT[(size_t)row * 256 + n0 + 16 * j + r16] =
            fast_exp2((sum[r] + bj) * LOG2E2);
      }
    }
  }
}

// ---------------------------------------------------------------------------
// Fused attention. 256 blocks, 1024 thr. XCD-swizzled so all 16 sg-blocks of
// a batch b land on one XCD (v[b]+EaT[b] become XCD-L2-resident).
// Score: thread = (dgf:32, t4:32). Each thread owns 8 d's, 4 t's, ALL 4 s's:
//   Ea float4 loaded ONCE and reused for 4 s.
//   sigmoid denominators D = 1 + Ea*Euh (exp2 pre-hoisted into GEMM).
//   Pairwise rcp merge: w0/D0 + w1/D1 = (w0*D1+w1*D0)/(D0*D1) -> rcps halved.
//   Cross-dgf: shfl_xor(32) pairs dgf 2w/2w+1, then pS[4][16][128] in LDS.
// Softmax over t: threads<512, wave shuffle + 2-wave LDS combine.
// Context: thread = (f:512, th:2); th = t-half, ALL 4 s-rows per thread —
//   no duplicate v reads; partials combined via LDS (reusing pS) + barrier.
// ---------------------------------------------------------------------------
__global__ __launch_bounds__(1024) void attn_fused_kernel(
    const float* __restrict__ EaT, const float* __restrict__ EuhT,
    const float* __restrict__ wg, const float* __restrict__ v,
    float* __restrict__ u) {
  __shared__ float EuhS[4 * 256];
  __shared__ float wS[256];
  __shared__ float pS[4 * 16 * 128];   // [s][wavepair][t]; reused as uP[2][4][512]
  __shared__ float bS[4 * 128];
  __shared__ float mW[8];
  __shared__ float sW[8];

  const int tid = threadIdx.x;
  // bijective XCD swizzle: round-robin dispatch puts bid&7 on XCD (bid&7);
  // give each XCD 2 full b's (16 sg-blocks each).
  const int bid  = blockIdx.x;
  const int slot = bid >> 3;
  const int b    = (bid & 7) * 2 + (slot >> 4);
  const int sg   = slot & 15;
  const int s0   = sg * 4;

  // ---- stage Euh (4x256, already exp2'd) and w (256) ----
  if (tid < 256) {
    const int row = tid >> 6, q4 = (tid & 63) << 2;
    *(float4*)&EuhS[row * 256 + q4] =
        *(const float4*)&EuhT[(size_t)(b * 64 + s0 + row) * 256 + q4];
  } else if (tid < 320) {
    const int q4 = (tid - 256) << 2;
    *(float4*)&wS[q4] = *(const float4*)&wg[q4];
  }
  __syncthreads();

  // ---- scores: thread = (dgf, t4); 8 d x 4 t x 4 s each ----
  {
    const int t4  = tid & 31;
    const int dgf = tid >> 5;                     // 0..31
    const float* eab = EaT + (size_t)b * 32768 + (size_t)dgf * 8 * 128 + t4 * 4;

    // preload Euh (4s x 8d) and w (8d) into registers (static-indexed)
    float eu[4][8];
    float wr[8];
#pragma unroll
    for (int s = 0; s < 4; s++) {
      *(float4*)&eu[s][0] = *(const float4*)&EuhS[s * 256 + dgf * 8];
      *(float4*)&eu[s][4] = *(const float4*)&EuhS[s * 256 + dgf * 8 + 4];
    }
    *(float4*)&wr[0] = *(const float4*)&wS[dgf * 8];
    *(float4*)&wr[4] = *(const float4*)&wS[dgf * 8 + 4];

    f32x4 acc[4];
#pragma unroll
    for (int s = 0; s < 4; s++) acc[s] = (f32x4){0.f, 0.f, 0.f, 0.f};

#pragma unroll
    for (int jp = 0; jp < 4; jp++) {            // 4 d-pairs
      float4 e0 = *(const float4*)(eab + (2 * jp + 0) * 128);
      float4 e1 = *(const float4*)(eab + (2 * jp + 1) * 128);
      const float w0 = wr[2 * jp], w1 = wr[2 * jp + 1];
#pragma unroll
      for (int s = 0; s < 4; s++) {
        const float u0 = eu[s][2 * jp], u1 = eu[s][2 * jp + 1];
        float D0, D1, num;
        D0 = fmaf(e0.x, u0, 1.0f); D1 = fmaf(e1.x, u1, 1.0f);
        num = fmaf(w1, D0, w0 * D1);
        acc[s][0] = fmaf(num, fast_rcp(D0 * D1), acc[s][0]);
        D0 = fmaf(e0.y, u0, 1.0f); D1 = fmaf(e1.y, u1, 1.0f);
        num = fmaf(w1, D0, w0 * D1);
        acc[s][1] = fmaf(num, fast_rcp(D0 * D1), acc[s][1]);
        D0 = fmaf(e0.z, u0, 1.0f); D1 = fmaf(e1.z, u1, 1.0f);
        num = fmaf(w1, D0, w0 * D1);
        acc[s][2] = fmaf(num, fast_rcp(D0 * D1), acc[s][2]);
        D0 = fmaf(e0.w, u0, 1.0f); D1 = fmaf(e1.w, u1, 1.0f);
        num = fmaf(w1, D0, w0 * D1);
        acc[s][3] = fmaf(num, fast_rcp(D0 * D1), acc[s][3]);
      }
    }

    // combine dgf pair (2w, 2w+1): lane l += lane l^32
#pragma unroll
    for (int s = 0; s < 4; s++) {
#pragma unroll
      for (int c = 0; c < 4; c++) acc[s][c] += __shfl_xor(acc[s][c], 32, 64);
    }
    const int wv_ = tid >> 6;                   // 0..15
    if ((tid & 63) < 32) {
#pragma unroll
      for (int s = 0; s < 4; s++) {
        float4 o = make_float4(acc[s][0], acc[s][1], acc[s][2], acc[s][3]);
        *(float4*)&pS[(s * 16 + wv_) * 128 + t4 * 4] = o;
      }
    }
  }
  __syncthreads();

  // ---- reduce over 16 wavepairs + softmax over t (threads < 512) ----
  float qv = 0.0f, ev = 0.0f;
  const int wvid = tid >> 6, lane = tid & 63;
  if (tid < 512) {
    const int s_l = tid >> 7, t = tid & 127;
    float ssum = 0.0f;
#pragma unroll
    for (int k = 0; k < 16; k++) ssum += pS[(s_l * 16 + k) * 128 + t];
    qv = ssum * (-LOG2E2);   // log2-domain score
    float m = qv;
#pragma unroll
    for (int off = 32; off > 0; off >>= 1) m = fmaxf(m, __shfl_xor(m, off, 64));
    if (lane == 0) mW[wvid] = m;
  }
  __syncthreads();
  if (tid < 512) {
    float m = fmaxf(mW[wvid], mW[wvid ^ 1]);
    ev = fast_exp2(qv - m);
    float ssum = ev;
#pragma unroll
    for (int off = 32; off > 0; off >>= 1) ssum += __shfl_xor(ssum, off, 64);
    if (lane == 0) sW[wvid] = ssum;
  }
  __syncthreads();
  if (tid < 512) {
    const int s_l = tid >> 7, t = tid & 127;
    bS[s_l * 128 + t] = ev * fast_rcp(sW[wvid] + sW[wvid ^ 1]);
  }
  __syncthreads();

  // ---- context: thread = (f:512, th:2); th = t-half, all 4 s-rows ----
  const int f  = tid & 511;
  const int th = tid >> 9;
  const float* vb2 = v + (size_t)b * TV * FF + (size_t)th * 64 * FF;
  const float* bsp = &bS[th * 64];
  float a0 = 0.f, a1 = 0.f, a2 = 0.f, a3 = 0.f;
#pragma unroll 4
  for (int tg = 0; tg < 64; tg += 4) {
    float4 b0 = *(const float4*)&bsp[0 * 128 + tg];
    float4 b1 = *(const float4*)&bsp[1 * 128 + tg];
    float4 b2 = *(const float4*)&bsp[2 * 128 + tg];
    float4 b3 = *(const float4*)&bsp[3 * 128 + tg];
    float v0 = vb2[(tg + 0) * 512 + f];
    float v1 = vb2[(tg + 1) * 512 + f];
    float v2 = vb2[(tg + 2) * 512 + f];
    float v3 = vb2[(tg + 3) * 512 + f];
    a0 = fmaf(b0.x, v0, a0); a0 = fmaf(b0.y, v1, a0);
    a0 = fmaf(b0.z, v2, a0); a0 = fmaf(b0.w, v3, a0);
    a1 = fmaf(b1.x, v0, a1); a1 = fmaf(b1.y, v1, a1);
    a1 = fmaf(b1.z, v2, a1); a1 = fmaf(b1.w, v3, a1);
    a2 = fmaf(b2.x, v0, a2); a2 = fmaf(b2.y, v1, a2);
    a2 = fmaf(b2.z, v2, a2); a2 = fmaf(b2.w, v3, a2);
    a3 = fmaf(b3.x, v0, a3); a3 = fmaf(b3.y, v1, a3);
    a3 = fmaf(b3.z, v2, a3); a3 = fmaf(b3.w, v3, a3);
  }
  // partials -> LDS (reuse pS as uP[th][s][f]); conflict-free (consecutive f)
  float* uP = pS;
  uP[(th * 4 + 0) * 512 + f] = a0;
  uP[(th * 4 + 1) * 512 + f] = a1;
  uP[(th * 4 + 2) * 512 + f] = a2;
  uP[(th * 4 + 3) * 512 + f] = a3;
  __syncthreads();
  // combine halves + store: 2048 outputs, 2 per thread, coalesced over f
  {
    int oi = tid;
#pragma unroll
    for (int rep = 0; rep < 2; rep++, oi += 1024) {
      const int s = oi >> 9, ff = oi & 511;
      const float val = uP[s * 512 + ff] + uP[(s + 4) * 512 + ff];
      u[(size_t)(b * 64 + s0 + s) * 512 + ff] = val;
    }
  }
}

extern "C" void kernel_launch(void* const* d_in, const int* in_sizes, int n_in,
                              void* d_out, int out_size, void* d_ws, size_t ws_size,
                              hipStream_t stream) {
  const float* v  = (const float*)d_in[0];  // [16,128,512]
  const float* h  = (const float*)d_in[1];  // [16,64,512]
  const float* W  = (const float*)d_in[2];  // [512,256]
  const float* U  = (const float*)d_in[3];  // [512,256]
  const float* bb = (const float*)d_in[4];  // [256]
  const float* w  = (const float*)d_in[5];  // [256,1]
  float* u = (float*)d_out;                 // [16,64,512]

  float* EaT  = (float*)d_ws;                      // [16][256][128] f32 = exp2(2Wv*log2e)
  float* EuhT = EaT + (size_t)2048 * 256;          // [1024,256] f32 = exp2(2(Uh+b)*log2e)
  unsigned short* WT = (unsigned short*)(EuhT + (size_t)1024 * 256);  // [256][512] bf16 (W^T)
  unsigned short* UT = WT + (size_t)256 * 512;                        // [256][512] bf16 (U^T)

  convert_wu_kernel<<<256, 256, 0, stream>>>(W, U, WT, UT);
  mfma_gemm_kernel<<<384, 256, 0, stream>>>(v, h, WT, UT, bb, EaT, EuhT);
  attn_fused_kernel<<<256, 1024, 0, stream>>>(EaT, EuhT, w, v, u);
}

// Round 4
// 87.830 us; speedup vs baseline: 1.0376x; 1.0061x over previous
//
#include <hip/hip_runtime.h>
#include <hip/hip_bf16.h>

// Problem constants: B=16, TV=128, TH=64, F=512, H=512, D=256
#define BB 16
#define TV 128
#define TH 64
#define FF 512
#define HH 512
#define DD 256

#define LOG2E2 2.8853900817779268f   // 2*log2(e): exp2(LOG2E2*x) = e^{2x}

typedef __attribute__((ext_vector_type(8))) short bf16x8;   // 8 bf16 = 4 VGPRs
typedef __attribute__((ext_vector_type(4))) float f32x4;
typedef __attribute__((ext_vector_type(2))) float f32x2;    // -> v_pk_*_f32

__device__ __forceinline__ float fast_exp2(float x) {
#if __has_builtin(__builtin_amdgcn_exp2f)
  return __builtin_amdgcn_exp2f(x);
#else
  return __expf(x * 0.6931471805599453f);
#endif
}
__device__ __forceinline__ float fast_rcp(float x) {
#if __has_builtin(__builtin_amdgcn_rcpf)
  return __builtin_amdgcn_rcpf(x);
#else
  return 1.0f / x;
#endif
}
__device__ __forceinline__ unsigned short f2bf(float x) {  // RNE fp32->bf16
  union { float f; unsigned u; } a; a.f = x;
  unsigned r = a.u + 0x7fffu + ((a.u >> 16) & 1u);
  return (unsigned short)(r >> 16);
}

// pack 8 f32 -> bf16x8 (RNE; compiler emits packed cvt — m240: scalar casts
// beat hand-written inline-asm cvt_pk)
__device__ __forceinline__ bf16x8 cvt8(const float4 x, const float4 y) {
  union { bf16x8 v; unsigned short e[8]; } r;
  r.e[0] = f2bf(x.x); r.e[1] = f2bf(x.y); r.e[2] = f2bf(x.z); r.e[3] = f2bf(x.w);
  r.e[4] = f2bf(y.x); r.e[5] = f2bf(y.y); r.e[6] = f2bf(y.z); r.e[7] = f2bf(y.w);
  return r.v;
}

// ---------------------------------------------------------------------------
// Mini convert: W,U -> bf16 TRANSPOSED ([n][k]) only. v/h are consumed as f32
// directly by the GEMM (in-register cvt). 65536 tasks, 256 blocks x 256 thr.
// ---------------------------------------------------------------------------
__global__ __launch_bounds__(256) void convert_wu_kernel(
    const float* __restrict__ W, const float* __restrict__ U,
    unsigned short* __restrict__ WT, unsigned short* __restrict__ UT) {
  int t2 = blockIdx.x * 256 + threadIdx.x;
  const float* S;
  unsigned short* Dt;
  if (t2 < 32768) { S = W; Dt = WT; } else { S = U; Dt = UT; t2 -= 32768; }
  int n = t2 & 255, k4 = t2 >> 8;           // k4 in [0,128)
  float a0 = S[(k4 * 4 + 0) * 256 + n];     // coalesced over n
  float a1 = S[(k4 * 4 + 1) * 256 + n];
  float a2 = S[(k4 * 4 + 2) * 256 + n];
  float a3 = S[(k4 * 4 + 3) * 256 + n];
  ushort4 o = make_ushort4(f2bf(a0), f2bf(a1), f2bf(a2), f2bf(a3));
  *(ushort4*)&Dt[(size_t)n * 512 + k4 * 4] = o;
}

// ---------------------------------------------------------------------------
// MFMA GEMM with 4-way K-split. 384 blocks * 256 thr (4 waves).
//   blocks [0,256):   EaT[b][d][t]  = exp2(LOG2E2 * (v @ W))   (TRANSPOSED)
//   blocks [256,384): EuhT[m][d]    = exp2(LOG2E2 * (h @ U + b))
// Block tile 32m x 64n x 512k; wave wv owns k in [wv*128, wv*128+128).
// NEW (R4): bijective XCD swizzle — consecutive phys blocks differ in nt
// (same mt); round-robin dispatch spread one A-panel's 4 nt-variants over 4
// XCDs (A fetched 4x). logical=(phys&7)*48+(phys>>3) gives each XCD a
// contiguous bid chunk = all nt's of its mt's -> A fetched once per XCD.
// Partials combined via 32 KB LDS; epilogue split across the 4 waves.
// C/D: col = l&15, row = (l>>4)*4 + reg   (m89-verified)
// ---------------------------------------------------------------------------
__global__ __launch_bounds__(256) void mfma_gemm_kernel(
    const float* __restrict__ Av, const float* __restrict__ Ah,
    const unsigned short* __restrict__ WT, const unsigned short* __restrict__ UT,
    const float* __restrict__ bias, float* __restrict__ EaT,
    float* __restrict__ EuhT) {
  __shared__ f32x4 cS[8][4][64];   // [slot=(i*4+j)][wv][lane]
  const int phys = blockIdx.x;
  const int bid  = (phys & 7) * 48 + (phys >> 3);   // 384 = 8 * 48, bijective
  const float* A;
  const unsigned short* BT;
  int mt, nt;
  bool is_wv;
  if (bid < 256) {
    A = Av; BT = WT; is_wv = true;
    mt = bid >> 2; nt = bid & 3;            // mt 0..63, nt 0..3
  } else {
    const int b2 = bid - 256;
    A = Ah; BT = UT; is_wv = false;
    mt = b2 >> 2; nt = b2 & 3;              // mt 0..31
  }
  const int tid  = threadIdx.x;
  const int wv   = tid >> 6;               // k-split index 0..3
  const int lane = tid & 63;
  const int m0   = mt * 32;
  const int n0   = nt * 64;
  const int r16  = lane & 15;
  const int quad = lane >> 4;

  const float* ap0 = A + (size_t)(m0 + r16) * 512 + wv * 128 + quad * 8;
  const float* ap1 = ap0 + 16 * 512;
  const unsigned short* bp0 = BT + (size_t)(n0 + r16) * 512 + wv * 128 + quad * 8;
  const unsigned short* bp1 = bp0 + 16 * 512;
  const unsigned short* bp2 = bp0 + 32 * 512;
  const unsigned short* bp3 = bp0 + 48 * 512;

  f32x4 acc[2][4];
#pragma unroll
  for (int i = 0; i < 2; i++)
#pragma unroll
    for (int j = 0; j < 4; j++) acc[i][j] = (f32x4){0.f, 0.f, 0.f, 0.f};

#pragma unroll
  for (int kc = 0; kc < 4; kc++) {          // 4 x 32k = this wave's 128k slice
    float4 a0lo = *(const float4*)(ap0 + kc * 32);
    float4 a0hi = *(const float4*)(ap0 + kc * 32 + 4);
    float4 a1lo = *(const float4*)(ap1 + kc * 32);
    float4 a1hi = *(const float4*)(ap1 + kc * 32 + 4);
    bf16x8 fa0 = cvt8(a0lo, a0hi);
    bf16x8 fa1 = cvt8(a1lo, a1hi);
    bf16x8 fb0 = *(const bf16x8*)(bp0 + kc * 32);
    bf16x8 fb1 = *(const bf16x8*)(bp1 + kc * 32);
    bf16x8 fb2 = *(const bf16x8*)(bp2 + kc * 32);
    bf16x8 fb3 = *(const bf16x8*)(bp3 + kc * 32);
    acc[0][0] = __builtin_amdgcn_mfma_f32_16x16x32_bf16(fa0, fb0, acc[0][0], 0, 0, 0);
    acc[0][1] = __builtin_amdgcn_mfma_f32_16x16x32_bf16(fa0, fb1, acc[0][1], 0, 0, 0);
    acc[0][2] = __builtin_amdgcn_mfma_f32_16x16x32_bf16(fa0, fb2, acc[0][2], 0, 0, 0);
    acc[0][3] = __builtin_amdgcn_mfma_f32_16x16x32_bf16(fa0, fb3, acc[0][3], 0, 0, 0);
    acc[1][0] = __builtin_amdgcn_mfma_f32_16x16x32_bf16(fa1, fb0, acc[1][0], 0, 0, 0);
    acc[1][1] = __builtin_amdgcn_mfma_f32_16x16x32_bf16(fa1, fb1, acc[1][1], 0, 0, 0);
    acc[1][2] = __builtin_amdgcn_mfma_f32_16x16x32_bf16(fa1, fb2, acc[1][2], 0, 0, 0);
    acc[1][3] = __builtin_amdgcn_mfma_f32_16x16x32_bf16(fa1, fb3, acc[1][3], 0, 0, 0);
  }

  // ---- K-partial exchange: all 4 waves write, epilogue split by slot ----
#pragma unroll
  for (int i = 0; i < 2; i++)
#pragma unroll
    for (int j = 0; j < 4; j++) cS[i * 4 + j][wv][lane] = acc[i][j];
  __syncthreads();

#pragma unroll
  for (int rep = 0; rep < 2; rep++) {
    const int slot = wv + rep * 4;          // wave wv handles slots wv, wv+4
    const int i = slot >> 2, j = slot & 3;
    f32x4 s0 = cS[slot][0][lane];
    f32x4 s1 = cS[slot][1][lane];
    f32x4 s2 = cS[slot][2][lane];
    f32x4 s3 = cS[slot][3][lane];
    f32x4 sum = (s0 + s1) + (s2 + s3);
    if (is_wv) {
      // transposed store: EaT[b*32768 + d*128 + t], d = n-col, t = m&127
      const int bb = m0 >> 7;
      const int tb = (m0 & 127) + 16 * i + quad * 4;
      float* Wb = EaT + (size_t)bb * 32768;
#pragma unroll
      for (int r = 0; r < 4; r++) {
        Wb[(size_t)(n0 + 16 * j + r16) * 128 + tb + r] =
            fast_exp2(sum[r] * LOG2E2);
      }
    } else {
      const float bj = bias[n0 + 16 * j + r16];
#pragma unroll
      for (int r = 0; r < 4; r++) {
        const int row = m0 + 16 * i + quad * 4 + r;
        EuhT[(size_t)row * 256 + n0 + 16 * j + r16] =
            fast_exp2((sum[r] + bj) * LOG2E2);
      }
    }
  }
}

// ---------------------------------------------------------------------------
// Fused attention. 256 blocks, 1024 thr. XCD-swizzled so all 16 sg-blocks of
// a batch b land on one XCD (v[b]+EaT[b] become XCD-L2-resident).
// Score: thread = (dgf:32, t4:32). Each thread owns 8 d's, 4 t's, ALL 4 s's.
//   NEW (R4): inner math restructured as f32x2 ext-vector ops so clang can
//   emit v_pk_fma_f32/v_pk_mul_f32 (dual-issue packed f32) — same fma tree,
//   bit-identical results, ~half the VALU issue slots.
//   sigmoid denominators D = 1 + Ea*Euh (exp2 pre-hoisted into GEMM).
//   Pairwise rcp merge: w0/D0 + w1/D1 = (w0*D1+w1*D0)/(D0*D1) -> rcps halved.
//   Cross-dgf: shfl_xor(32) pairs dgf 2w/2w+1, then pS[4][16][128] in LDS.
// Softmax over t: threads<512, wave shuffle + 2-wave LDS combine.
// Context: thread = (f:512, th:2); th = t-half, ALL 4 s-rows per thread,
//   s-accumulators pk-paired; partials combined via LDS (reuse pS) + barrier.
// ---------------------------------------------------------------------------
__global__ __launch_bounds__(1024) void attn_fused_kernel(
    const float* __restrict__ EaT, const float* __restrict__ EuhT,
    const float* __restrict__ wg, const float* __restrict__ v,
    float* __restrict__ u) {
  __shared__ float EuhS[4 * 256];
  __shared__ float wS[256];
  __shared__ float pS[4 * 16 * 128];   // [s][wavepair][t]; reused as uP[2][4][512]
  __shared__ float bS[4 * 128];
  __shared__ float mW[8];
  __shared__ float sW[8];

  const int tid = threadIdx.x;
  // bijective XCD swizzle: round-robin dispatch puts bid&7 on XCD (bid&7);
  // give each XCD 2 full b's (16 sg-blocks each).
  const int bid  = blockIdx.x;
  const int slot = bid >> 3;
  const int b    = (bid & 7) * 2 + (slot >> 4);
  const int sg   = slot & 15;
  const int s0   = sg * 4;

  // ---- stage Euh (4x256, already exp2'd) and w (256) ----
  if (tid < 256) {
    const int row = tid >> 6, q4 = (tid & 63) << 2;
    *(float4*)&EuhS[row * 256 + q4] =
        *(const float4*)&EuhT[(size_t)(b * 64 + s0 + row) * 256 + q4];
  } else if (tid < 320) {
    const int q4 = (tid - 256) << 2;
    *(float4*)&wS[q4] = *(const float4*)&wg[q4];
  }
  __syncthreads();

  // ---- scores: thread = (dgf, t4); 8 d x 4 t x 4 s each ----
  {
    const int t4  = tid & 31;
    const int dgf = tid >> 5;                     // 0..31
    const float* eab = EaT + (size_t)b * 32768 + (size_t)dgf * 8 * 128 + t4 * 4;

    // preload Euh (4s x 8d) and w (8d) into registers (static-indexed)
    float eu[4][8];
    float wr[8];
#pragma unroll
    for (int s = 0; s < 4; s++) {
      *(float4*)&eu[s][0] = *(const float4*)&EuhS[s * 256 + dgf * 8];
      *(float4*)&eu[s][4] = *(const float4*)&EuhS[s * 256 + dgf * 8 + 4];
    }
    *(float4*)&wr[0] = *(const float4*)&wS[dgf * 8];
    *(float4*)&wr[4] = *(const float4*)&wS[dgf * 8 + 4];

    f32x2 accL[4], accH[4];
#pragma unroll
    for (int s = 0; s < 4; s++) {
      accL[s] = (f32x2){0.f, 0.f};
      accH[s] = (f32x2){0.f, 0.f};
    }

#pragma unroll
    for (int jp = 0; jp < 4; jp++) {            // 4 d-pairs
      float4 e0 = *(const float4*)(eab + (2 * jp + 0) * 128);
      float4 e1 = *(const float4*)(eab + (2 * jp + 1) * 128);
      const f32x2 e0L = (f32x2){e0.x, e0.y}, e0H = (f32x2){e0.z, e0.w};
      const f32x2 e1L = (f32x2){e1.x, e1.y}, e1H = (f32x2){e1.z, e1.w};
      const float w0 = wr[2 * jp], w1 = wr[2 * jp + 1];
#pragma unroll
      for (int s = 0; s < 4; s++) {
        const float u0 = eu[s][2 * jp], u1 = eu[s][2 * jp + 1];
        // packed: D0 = 1 + e0*u0, D1 = 1 + e1*u1 (per t-element)
        f32x2 D0L = e0L * u0 + 1.0f;
        f32x2 D1L = e1L * u1 + 1.0f;
        f32x2 numL = w1 * D0L + w0 * D1L;
        f32x2 PL = D0L * D1L;
        f32x2 rL = (f32x2){fast_rcp(PL.x), fast_rcp(PL.y)};
        accL[s] = numL * rL + accL[s];

        f32x2 D0H = e0H * u0 + 1.0f;
        f32x2 D1H = e1H * u1 + 1.0f;
        f32x2 numH = w1 * D0H + w0 * D1H;
        f32x2 PH = D0H * D1H;
        f32x2 rH = (f32x2){fast_rcp(PH.x), fast_rcp(PH.y)};
        accH[s] = numH * rH + accH[s];
      }
    }

    // combine dgf pair (2w, 2w+1): lane l += lane l^32
#pragma unroll
    for (int s = 0; s < 4; s++) {
      accL[s].x += __shfl_xor(accL[s].x, 32, 64);
      accL[s].y += __shfl_xor(accL[s].y, 32, 64);
      accH[s].x += __shfl_xor(accH[s].x, 32, 64);
      accH[s].y += __shfl_xor(accH[s].y, 32, 64);
    }
    const int wv_ = tid >> 6;                   // 0..15
    if ((tid & 63) < 32) {
#pragma unroll
      for (int s = 0; s < 4; s++) {
        float4 o = make_float4(accL[s].x, accL[s].y, accH[s].x, accH[s].y);
        *(float4*)&pS[(s * 16 + wv_) * 128 + t4 * 4] = o;
      }
    }
  }
  __syncthreads();

  // ---- reduce over 16 wavepairs + softmax over t (threads < 512) ----
  float qv = 0.0f, ev = 0.0f;
  const int wvid = tid >> 6, lane = tid & 63;
  if (tid < 512) {
    const int s_l = tid >> 7, t = tid & 127;
    float ssum = 0.0f;
#pragma unroll
    for (int k = 0; k < 16; k++) ssum += pS[(s_l * 16 + k) * 128 + t];
    qv = ssum * (-LOG2E2);   // log2-domain score
    float m = qv;
#pragma unroll
    for (int off = 32; off > 0; off >>= 1) m = fmaxf(m, __shfl_xor(m, off, 64));
    if (lane == 0) mW[wvid] = m;
  }
  __syncthreads();
  if (tid < 512) {
    float m = fmaxf(mW[wvid], mW[wvid ^ 1]);
    ev = fast_exp2(qv - m);
    float ssum = ev;
#pragma unroll
    for (int off = 32; off > 0; off >>= 1) ssum += __shfl_xor(ssum, off, 64);
    if (lane == 0) sW[wvid] = ssum;
  }
  __syncthreads();
  if (tid < 512) {
    const int s_l = tid >> 7, t = tid & 127;
    bS[s_l * 128 + t] = ev * fast_rcp(sW[wvid] + sW[wvid ^ 1]);
  }
  __syncthreads();

  // ---- context: thread = (f:512, th:2); th = t-half, all 4 s-rows ----
  const int f  = tid & 511;
  const int th = tid >> 9;
  const float* vb2 = v + (size_t)b * TV * FF + (size_t)th * 64 * FF;
  const float* bsp = &bS[th * 64];
  f32x2 a01 = (f32x2){0.f, 0.f};     // s-rows {0,1} pk-paired
  f32x2 a23 = (f32x2){0.f, 0.f};     // s-rows {2,3}
#pragma unroll 4
  for (int tg = 0; tg < 64; tg += 4) {
    float4 b0 = *(const float4*)&bsp[0 * 128 + tg];
    float4 b1 = *(const float4*)&bsp[1 * 128 + tg];
    float4 b2 = *(const float4*)&bsp[2 * 128 + tg];
    float4 b3 = *(const float4*)&bsp[3 * 128 + tg];
    float v0 = vb2[(tg + 0) * 512 + f];
    float v1 = vb2[(tg + 1) * 512 + f];
    float v2 = vb2[(tg + 2) * 512 + f];
    float v3 = vb2[(tg + 3) * 512 + f];
    a01 = v0 * (f32x2){b0.x, b1.x} + a01;
    a23 = v0 * (f32x2){b2.x, b3.x} + a23;
    a01 = v1 * (f32x2){b0.y, b1.y} + a01;
    a23 = v1 * (f32x2){b2.y, b3.y} + a23;
    a01 = v2 * (f32x2){b0.z, b1.z} + a01;
    a23 = v2 * (f32x2){b2.z, b3.z} + a23;
    a01 = v3 * (f32x2){b0.w, b1.w} + a01;
    a23 = v3 * (f32x2){b2.w, b3.w} + a23;
  }
  // partials -> LDS (reuse pS as uP[th][s][f]); conflict-free (consecutive f)
  float* uP = pS;
  uP[(th * 4 + 0) * 512 + f] = a01.x;
  uP[(th * 4 + 1) * 512 + f] = a01.y;
  uP[(th * 4 + 2) * 512 + f] = a23.x;
  uP[(th * 4 + 3) * 512 + f] = a23.y;
  __syncthreads();
  // combine halves + store: 2048 outputs, 2 per thread, coalesced over f
  {
    int oi = tid;
#pragma unroll
    for (int rep = 0; rep < 2; rep++, oi += 1024) {
      const int s = oi >> 9, ff = oi & 511;
      const float val = uP[s * 512 + ff] + uP[(s + 4) * 512 + ff];
      u[(size_t)(b * 64 + s0 + s) * 512 + ff] = val;
    }
  }
}

extern "C" void kernel_launch(void* const* d_in, const int* in_sizes, int n_in,
                              void* d_out, int out_size, void* d_ws, size_t ws_size,
                              hipStream_t stream) {
  const float* v  = (const float*)d_in[0];  // [16,128,512]
  const float* h  = (const float*)d_in[1];  // [16,64,512]
  const float* W  = (const float*)d_in[2];  // [512,256]
  const float* U  = (const float*)d_in[3];  // [512,256]
  const float* bb = (const float*)d_in[4];  // [256]
  const float* w  = (const float*)d_in[5];  // [256,1]
  float* u = (float*)d_out;                 // [16,64,512]

  float* EaT  = (float*)d_ws;                      // [16][256][128] f32 = exp2(2Wv*log2e)
  float* EuhT = EaT + (size_t)2048 * 256;          // [1024,256] f32 = exp2(2(Uh+b)*log2e)
  unsigned short* WT = (unsigned short*)(EuhT + (size_t)1024 * 256);  // [256][512] bf16 (W^T)
  unsigned short* UT = WT + (size_t)256 * 512;                        // [256][512] bf16 (U^T)

  convert_wu_kernel<<<256, 256, 0, stream>>>(W, U, WT, UT);
  mfma_gemm_kernel<<<384, 256, 0, stream>>>(v, h, WT, UT, bb, EaT, EuhT);
  attn_fused_kernel<<<256, 1024, 0, stream>>>(EaT, EuhT, w, v, u);
}